// Round 14
// baseline (211.938 us; speedup 1.0000x reference)
//
#include <hip/hip_runtime.h>
#include <hip/hip_bf16.h>
#include <math.h>

#define CH 128
#define PSHIFT 8              // 256 nodes per partition
#define PSIZE (1 << PSHIFT)
#define CHUNK 4096            // edges per block in k_part
#define EPT 16                // edges per thread (256 * 16 = 4096)
#define MAXP 256              // max partitions
#define PCAP 12288            // staging capacity per partition

typedef __attribute__((ext_vector_type(8))) short short8;
typedef __attribute__((ext_vector_type(4))) float f32x4;

__device__ __forceinline__ float seluf(float x) {
    const float scale = 1.0507009873554804934193349852946f;
    const float alpha = 1.6732632423543772848170429916717f;
    return x > 0.0f ? scale * x : scale * alpha * (__expf(x) - 1.0f);
}

__device__ __forceinline__ float lrelu(float x) {
    return x > 0.0f ? x : 0.2f * x;
}

__device__ __forceinline__ short bfc(float f) {
    union { __hip_bfloat16 b; short s; } u;
    u.b = __float2bfloat16(f);
    return u.s;
}

__device__ __forceinline__ unsigned pk(float lo, float hi) {
    return ((unsigned)(unsigned short)bfc(hi) << 16) | (unsigned short)bfc(lo);
}

// ---- CSR build pass A: 4B records ((dst-d0)<<24 | src), src < 2^24 ---------

__global__ __launch_bounds__(256) void k_part(const int* __restrict__ ei,
                                              int* __restrict__ pfill,
                                              unsigned* __restrict__ staged,
                                              int E, int NP) {
    __shared__ int hist[MAXP];
    __shared__ int base[MAXP];
    const int tid = threadIdx.x;
    const int j0 = blockIdx.x * CHUNK;
    for (int i = tid; i < NP; i += 256) hist[i] = 0;
    __syncthreads();
    int part[EPT], rank[EPT];
    unsigned rec[EPT];
#pragma unroll
    for (int e = 0; e < EPT; ++e) {
        int j = j0 + e * 256 + tid;
        part[e] = -1;
        if (j < E) {
            int s = ei[j], d = ei[E + j];
            part[e] = d >> PSHIFT;
            rec[e] = ((unsigned)(d & (PSIZE - 1)) << 24) | (unsigned)s;
            rank[e] = atomicAdd(&hist[part[e]], 1);
        }
    }
    __syncthreads();
    for (int i = tid; i < NP; i += 256)
        base[i] = hist[i] ? atomicAdd(&pfill[i], hist[i]) : 0;
    __syncthreads();
#pragma unroll
    for (int e = 0; e < EPT; ++e)
        if (part[e] >= 0)
            staged[(size_t)part[e] * PCAP + base[part[e]] + rank[e]] = rec[e];
}

// ---- fat kernel: CSR build pass B (blocks < NP) || GEMM layer 1 (rest) -----

__global__ __launch_bounds__(256) void k_fat(
    const unsigned* __restrict__ staged, const int* __restrict__ pfill,
    int* __restrict__ rowptr, int* __restrict__ csr, int n, int E, int NP,
    const float* __restrict__ x, const float* __restrict__ W,
    const float* __restrict__ a_s, const float* __restrict__ a_d,
    __hip_bfloat16* __restrict__ hb, float* __restrict__ as_o,
    float* __restrict__ ad_o) {
    __shared__ __align__(16) char sm[32768];
    const int tid = threadIdx.x;

    if ((int)blockIdx.x < NP) {
        // ---------------- build path ----------------
        int* lcnt = (int*)sm;            // [256]
        int* lrow = lcnt + PSIZE;        // [256]
        int* sc   = lrow + PSIZE;        // [256]
        int* psc  = sc + PSIZE;          // [256]
        const int p = blockIdx.x;
        const int d0 = p << PSHIFT;
        psc[tid] = (tid < NP) ? pfill[tid] : 0;
        lcnt[tid] = 0;
        __syncthreads();
        for (int off = 1; off < 256; off <<= 1) {
            int v = (tid >= off) ? psc[tid - off] : 0;
            __syncthreads();
            psc[tid] += v;
            __syncthreads();
        }
        const int pbase = psc[p] - pfill[p];
        const size_t rbeg = (size_t)p * PCAP;
        const size_t rend = rbeg + pfill[p];
        const int rb = pbase + d0;
        for (size_t r = rbeg + tid; r < rend; r += 256)
            atomicAdd(&lcnt[staged[r] >> 24], 1);
        __syncthreads();
        int myv = (d0 + tid < n) ? lcnt[tid] + 1 : 0;
        sc[tid] = myv;
        __syncthreads();
        for (int off = 1; off < 256; off <<= 1) {
            int v = (tid >= off) ? sc[tid - off] : 0;
            __syncthreads();
            sc[tid] += v;
            __syncthreads();
        }
        if (d0 + tid < n) {
            int rp = rb + sc[tid] - myv;
            lrow[tid] = rp;
            rowptr[d0 + tid] = rp;
            csr[rp] = d0 + tid;              // self loop
            lcnt[tid] = 0;                   // reuse as fill counter
        }
        if (p == 0 && tid == 0) rowptr[n] = E + n;
        __syncthreads();
        for (size_t r = rbeg + tid; r < rend; r += 256) {
            unsigned v = staged[r];
            int dd = v >> 24, s = (int)(v & 0xFFFFFFu);
            int pos = lrow[dd] + 1 + atomicAdd(&lcnt[dd], 1);
            csr[pos] = s;
        }
        return;
    }

    // ---------------- gemm path (layer 1, fp32 input) ----------------
    short* WB = (short*)sm;                  // 32 KB
    for (int i = tid; i < CH * CH; i += 256) {
        int k = i >> 7, c = i & 127;
        int kb = k >> 5, kk = k & 31;
        int t = c >> 4;
        int ln = (c & 15) | ((kk >> 3) << 4);
        int j = kk & 7;
        WB[(((kb << 3) + t) << 9) + (ln << 3) + j] = bfc(W[i]);
    }
    __syncthreads();
    const int bid = blockIdx.x - NP;
    const int lane = tid & 63;
    const int wid = tid >> 6;
    const int l15 = lane & 15;
    const int lhi = lane >> 4;
    float asl[8], adl[8];
#pragma unroll
    for (int t = 0; t < 8; ++t) {
        asl[t] = a_s[t * 16 + l15];
        adl[t] = a_d[t * 16 + l15];
    }
#pragma unroll
    for (int s = 0; s < 2; ++s) {
        int r0 = bid * 128 + s * 64 + wid * 16;
        if (r0 >= n) break;
        int ar = r0 + l15; if (ar >= n) ar = n - 1;
        const float* xr = x + (size_t)ar * CH + lhi * 8;
        f32x4 acc[8];
#pragma unroll
        for (int t = 0; t < 8; ++t) acc[t] = (f32x4){0.f, 0.f, 0.f, 0.f};
#pragma unroll
        for (int kb = 0; kb < 4; ++kb) {
            float4 xa = *(const float4*)(xr + kb * 32);
            float4 xb = *(const float4*)(xr + kb * 32 + 4);
            short8 af;
            af[0] = bfc(xa.x); af[1] = bfc(xa.y); af[2] = bfc(xa.z); af[3] = bfc(xa.w);
            af[4] = bfc(xb.x); af[5] = bfc(xb.y); af[6] = bfc(xb.z); af[7] = bfc(xb.w);
#pragma unroll
            for (int t = 0; t < 8; ++t) {
                short8 bv = ((const short8*)WB)[(((kb << 3) + t) << 6) | lane];
                acc[t] = __builtin_amdgcn_mfma_f32_16x16x32_bf16(af, bv, acc[t], 0, 0, 0);
            }
        }
        float pa[4] = {0.f, 0.f, 0.f, 0.f}, pd[4] = {0.f, 0.f, 0.f, 0.f};
#pragma unroll
        for (int t = 0; t < 8; ++t) {
#pragma unroll
            for (int q = 0; q < 4; ++q) {
                int row = r0 + lhi * 4 + q;
                if (row < n)
                    hb[(size_t)row * CH + t * 16 + l15] = __float2bfloat16(acc[t][q]);
                pa[q] += acc[t][q] * asl[t];
                pd[q] += acc[t][q] * adl[t];
            }
        }
#pragma unroll
        for (int q = 0; q < 4; ++q) {
#pragma unroll
            for (int o = 1; o < 16; o <<= 1) {
                pa[q] += __shfl_xor(pa[q], o);
                pd[q] += __shfl_xor(pd[q], o);
            }
        }
        if (l15 == 0) {
#pragma unroll
            for (int q = 0; q < 4; ++q) {
                int row = r0 + lhi * 4 + q;
                if (row < n) { as_o[row] = pa[q]; ad_o[row] = pd[q]; }
            }
        }
    }
}

// ---- GEMM v3 (standalone, layer 2 bf16 input) ------------------------------

template <typename T>
__global__ __launch_bounds__(256) void k_gemm3(
    const T* __restrict__ x, const float* __restrict__ W,
    const float* __restrict__ a_s, const float* __restrict__ a_d,
    __hip_bfloat16* __restrict__ hb, float* __restrict__ as_o,
    float* __restrict__ ad_o, int n) {
    __shared__ short WB[4 * 8 * 64 * 8];   // 32 KB
    const int tid = threadIdx.x;
    for (int i = tid; i < CH * CH; i += 256) {
        int k = i >> 7, c = i & 127;
        int kb = k >> 5, kk = k & 31;
        int t = c >> 4;
        int ln = (c & 15) | ((kk >> 3) << 4);
        int j = kk & 7;
        WB[(((kb << 3) + t) << 9) + (ln << 3) + j] = bfc(W[i]);
    }
    __syncthreads();
    const int lane = tid & 63;
    const int wid = tid >> 6;
    const int l15 = lane & 15;
    const int lhi = lane >> 4;
    float asl[8], adl[8];
#pragma unroll
    for (int t = 0; t < 8; ++t) {
        asl[t] = a_s[t * 16 + l15];
        adl[t] = a_d[t * 16 + l15];
    }
#pragma unroll
    for (int s = 0; s < 2; ++s) {
        int r0 = blockIdx.x * 128 + s * 64 + wid * 16;
        if (r0 >= n) break;
        int ar = r0 + l15; if (ar >= n) ar = n - 1;
        const T* xr = x + (size_t)ar * CH + lhi * 8;
        f32x4 acc[8];
#pragma unroll
        for (int t = 0; t < 8; ++t) acc[t] = (f32x4){0.f, 0.f, 0.f, 0.f};
#pragma unroll
        for (int kb = 0; kb < 4; ++kb) {
            short8 af;
            if constexpr (sizeof(T) == 4) {
                float4 xa = *(const float4*)(xr + kb * 32);
                float4 xb = *(const float4*)(xr + kb * 32 + 4);
                af[0] = bfc(xa.x); af[1] = bfc(xa.y); af[2] = bfc(xa.z); af[3] = bfc(xa.w);
                af[4] = bfc(xb.x); af[5] = bfc(xb.y); af[6] = bfc(xb.z); af[7] = bfc(xb.w);
            } else {
                af = *(const short8*)(xr + kb * 32);
            }
#pragma unroll
            for (int t = 0; t < 8; ++t) {
                short8 bv = ((const short8*)WB)[(((kb << 3) + t) << 6) | lane];
                acc[t] = __builtin_amdgcn_mfma_f32_16x16x32_bf16(af, bv, acc[t], 0, 0, 0);
            }
        }
        float pa[4] = {0.f, 0.f, 0.f, 0.f}, pd[4] = {0.f, 0.f, 0.f, 0.f};
#pragma unroll
        for (int t = 0; t < 8; ++t) {
#pragma unroll
            for (int q = 0; q < 4; ++q) {
                int row = r0 + lhi * 4 + q;
                if (row < n)
                    hb[(size_t)row * CH + t * 16 + l15] = __float2bfloat16(acc[t][q]);
                pa[q] += acc[t][q] * asl[t];
                pd[q] += acc[t][q] * adl[t];
            }
        }
#pragma unroll
        for (int q = 0; q < 4; ++q) {
#pragma unroll
            for (int o = 1; o < 16; o <<= 1) {
                pa[q] += __shfl_xor(pa[q], o);
                pd[q] += __shfl_xor(pd[q], o);
            }
        }
        if (l15 == 0) {
#pragma unroll
            for (int q = 0; q < 4; ++q) {
                int row = r0 + lhi * 4 + q;
                if (row < n) { as_o[row] = pa[q]; ad_o[row] = pd[q]; }
            }
        }
    }
}

// ---- fused softmax + aggregation: channel-half split per XCD ---------------
// Grid = 2x node cover. half = (bid>>2)&1 so XCDs 0-3 own channels 0-63 and
// XCDs 4-7 own 64-127 (blockIdx%8 = XCD round-robin heuristic). Each XCD's
// gather footprint halves (6.4MB) -> compulsory L2-miss traffic ~halves.
// Wave = 1 node: softmax over 64 lanes, gather with 8 chan-lanes x 8 slots.

__global__ __launch_bounds__(256) void k_fused_agg(
    const int* __restrict__ rowptr, const int* __restrict__ csr,
    const float* __restrict__ as_v, const float* __restrict__ ad_v,
    float* __restrict__ wedge, const __hip_bfloat16* __restrict__ hb,
    const float* __restrict__ bias, __hip_bfloat16* __restrict__ out, int n) {
    const int bid = blockIdx.x;
    const int half = (bid >> 2) & 1;
    const int g = (bid >> 3) * 4 + (bid & 3);
    const int gw = g * 4 + (threadIdx.x >> 6);
    const int lane = threadIdx.x & 63;
    if (gw >= n) return;
    int beg = rowptr[gw], end = rowptr[gw + 1];
    int deg = end - beg;
    float adi = ad_v[gw];

    const int grp = lane >> 3;         // edge slot group 0..7
    const int c8 = lane & 7;           // 16B channel slot within half
    const int hoff = half * 8;         // uint4 offset into row
    float acc[8];
#pragma unroll
    for (int k = 0; k < 8; ++k) acc[k] = 0.f;
    float inv;

    if (deg <= 64) {
        bool valid = lane < deg;
        int src = valid ? csr[beg + lane] : 0;
        float e = valid ? lrelu(as_v[src] + adi) : -1e30f;
        float m = e;
#pragma unroll
        for (int o = 32; o > 0; o >>= 1) m = fmaxf(m, __shfl_xor(m, o));
        float w = valid ? __expf(e - m) : 0.f;
        float s = w;
#pragma unroll
        for (int o = 32; o > 0; o >>= 1) s += __shfl_xor(s, o);
        inv = 1.0f / s;
        // 16 slots/iter; slots >= deg carry w=0, src=0; indices always < 64.
        for (int b = 0; b < deg; b += 16) {
            int i0 = b + grp;          // <= 48+7 = 55
            int i1 = b + 8 + grp;      // <= 63
            float w0 = __shfl(w, i0), w1 = __shfl(w, i1);
            int s0 = __shfl(src, i0), s1 = __shfl(src, i1);
            uint4 hv0 = ((const uint4*)hb)[(size_t)s0 * 16 + hoff + c8];
            uint4 hv1 = ((const uint4*)hb)[(size_t)s1 * 16 + hoff + c8];
            acc[0] += w0 * __uint_as_float(hv0.x << 16);
            acc[1] += w0 * __uint_as_float(hv0.x & 0xffff0000u);
            acc[2] += w0 * __uint_as_float(hv0.y << 16);
            acc[3] += w0 * __uint_as_float(hv0.y & 0xffff0000u);
            acc[4] += w0 * __uint_as_float(hv0.z << 16);
            acc[5] += w0 * __uint_as_float(hv0.z & 0xffff0000u);
            acc[6] += w0 * __uint_as_float(hv0.w << 16);
            acc[7] += w0 * __uint_as_float(hv0.w & 0xffff0000u);
            acc[0] += w1 * __uint_as_float(hv1.x << 16);
            acc[1] += w1 * __uint_as_float(hv1.x & 0xffff0000u);
            acc[2] += w1 * __uint_as_float(hv1.y << 16);
            acc[3] += w1 * __uint_as_float(hv1.y & 0xffff0000u);
            acc[4] += w1 * __uint_as_float(hv1.z << 16);
            acc[5] += w1 * __uint_as_float(hv1.z & 0xffff0000u);
            acc[6] += w1 * __uint_as_float(hv1.w << 16);
            acc[7] += w1 * __uint_as_float(hv1.w & 0xffff0000u);
        }
    } else {
        // fallback (rare): wedge-array path; both halves write identical values
        float m = -1e30f;
        for (int p = beg + lane; p < end; p += 64) {
            float e = lrelu(as_v[csr[p]] + adi);
            wedge[p] = e;
            m = fmaxf(m, e);
        }
#pragma unroll
        for (int o = 32; o > 0; o >>= 1) m = fmaxf(m, __shfl_xor(m, o));
        float s = 0.f;
        for (int p = beg + lane; p < end; p += 64) {
            float wv = __expf(wedge[p] - m);
            wedge[p] = wv;
            s += wv;
        }
#pragma unroll
        for (int o = 32; o > 0; o >>= 1) s += __shfl_xor(s, o);
        inv = 1.0f / s;
        for (int p = beg; p < end; p += 16) {
            int p0 = p + grp, p1 = p + 8 + grp;
            float w0 = 0.f, w1 = 0.f;
            int s0 = 0, s1 = 0;
            if (p0 < end) { w0 = wedge[p0]; s0 = csr[p0]; }
            if (p1 < end) { w1 = wedge[p1]; s1 = csr[p1]; }
            uint4 hv0 = ((const uint4*)hb)[(size_t)s0 * 16 + hoff + c8];
            uint4 hv1 = ((const uint4*)hb)[(size_t)s1 * 16 + hoff + c8];
            acc[0] += w0 * __uint_as_float(hv0.x << 16);
            acc[1] += w0 * __uint_as_float(hv0.x & 0xffff0000u);
            acc[2] += w0 * __uint_as_float(hv0.y << 16);
            acc[3] += w0 * __uint_as_float(hv0.y & 0xffff0000u);
            acc[4] += w0 * __uint_as_float(hv0.z << 16);
            acc[5] += w0 * __uint_as_float(hv0.z & 0xffff0000u);
            acc[6] += w0 * __uint_as_float(hv0.w << 16);
            acc[7] += w0 * __uint_as_float(hv0.w & 0xffff0000u);
            acc[0] += w1 * __uint_as_float(hv1.x << 16);
            acc[1] += w1 * __uint_as_float(hv1.x & 0xffff0000u);
            acc[2] += w1 * __uint_as_float(hv1.y << 16);
            acc[3] += w1 * __uint_as_float(hv1.y & 0xffff0000u);
            acc[4] += w1 * __uint_as_float(hv1.z << 16);
            acc[5] += w1 * __uint_as_float(hv1.z & 0xffff0000u);
            acc[6] += w1 * __uint_as_float(hv1.w << 16);
            acc[7] += w1 * __uint_as_float(hv1.w & 0xffff0000u);
        }
    }
    // reduce across the 8 slot groups (offsets 8,16,32)
#pragma unroll
    for (int k = 0; k < 8; ++k) {
        acc[k] += __shfl_xor(acc[k], 8);
        acc[k] += __shfl_xor(acc[k], 16);
        acc[k] += __shfl_xor(acc[k], 32);
    }
    if (grp == 0) {
        const float4 bv0 = ((const float4*)bias)[half * 16 + c8 * 2];
        const float4 bv1 = ((const float4*)bias)[half * 16 + c8 * 2 + 1];
        float o0 = seluf(acc[0] * inv + bv0.x);
        float o1 = seluf(acc[1] * inv + bv0.y);
        float o2 = seluf(acc[2] * inv + bv0.z);
        float o3 = seluf(acc[3] * inv + bv0.w);
        float o4 = seluf(acc[4] * inv + bv1.x);
        float o5 = seluf(acc[5] * inv + bv1.y);
        float o6 = seluf(acc[6] * inv + bv1.z);
        float o7 = seluf(acc[7] * inv + bv1.w);
        uint4 ov;
        ov.x = pk(o0, o1);
        ov.y = pk(o2, o3);
        ov.z = pk(o4, o5);
        ov.w = pk(o6, o7);
        ((uint4*)out)[(size_t)gw * 16 + hoff + c8] = ov;
    }
}

// ---- global mean pool: single launch, 16 waves per graph -------------------

__device__ int lower_bound_dev(const int* a, int n, int key) {
    int lo = 0, hi = n;
    while (lo < hi) {
        int mid = (lo + hi) >> 1;
        if (a[mid] < key) lo = mid + 1; else hi = mid;
    }
    return lo;
}

__global__ __launch_bounds__(1024) void k_pool(const __hip_bfloat16* __restrict__ x,
                                               const int* __restrict__ batchv,
                                               float* __restrict__ outp, int n) {
    int g = blockIdx.x;
    int lo = lower_bound_dev(batchv, n, g);
    int hi = lower_bound_dev(batchv, n, g + 1);
    int lane = threadIdx.x & 63, wv = threadIdx.x >> 6;   // wv: 0..15
    float sx0 = 0.f, sy0 = 0.f, sx1 = 0.f, sy1 = 0.f;
    int i = lo + wv;
    for (; i + 16 < hi; i += 32) {
        unsigned u0 = ((const unsigned*)x)[(size_t)i * 64 + lane];
        unsigned u1 = ((const unsigned*)x)[(size_t)(i + 16) * 64 + lane];
        sx0 += __uint_as_float(u0 << 16);
        sy0 += __uint_as_float(u0 & 0xffff0000u);
        sx1 += __uint_as_float(u1 << 16);
        sy1 += __uint_as_float(u1 & 0xffff0000u);
    }
    if (i < hi) {
        unsigned u0 = ((const unsigned*)x)[(size_t)i * 64 + lane];
        sx0 += __uint_as_float(u0 << 16);
        sy0 += __uint_as_float(u0 & 0xffff0000u);
    }
    __shared__ float2 red[16][64];
    red[wv][lane] = make_float2(sx0 + sx1, sy0 + sy1);
    __syncthreads();
    if (wv == 0) {
        float ax = 0.f, ay = 0.f;
#pragma unroll
        for (int s = 0; s < 16; ++s) { ax += red[s][lane].x; ay += red[s][lane].y; }
        int cnt = hi - lo; if (cnt < 1) cnt = 1;
        float invc = 1.0f / (float)cnt;
        outp[(size_t)g * CH + 2 * lane] = ax * invc;
        outp[(size_t)g * CH + 2 * lane + 1] = ay * invc;
    }
}

// ---- orchestration ---------------------------------------------------------

extern "C" void kernel_launch(void* const* d_in, const int* in_sizes, int n_in,
                              void* d_out, int out_size, void* d_ws, size_t ws_size,
                              hipStream_t stream) {
    const float* u   = (const float*)d_in[0];
    const float* W1  = (const float*)d_in[1];
    const float* as1 = (const float*)d_in[2];
    const float* ad1 = (const float*)d_in[3];
    const float* b1  = (const float*)d_in[4];
    const float* W2  = (const float*)d_in[5];
    const float* as2 = (const float*)d_in[6];
    const float* ad2 = (const float*)d_in[7];
    const float* b2  = (const float*)d_in[8];
    const int* ei    = (const int*)d_in[9];
    const int* batchv= (const int*)d_in[10];

    const int N = in_sizes[0] / CH;
    const int E = in_sizes[9] / 2;
    const int M = E + N;
    const int NP = (N + PSIZE - 1) >> PSHIFT;
    const int G = out_size / CH;

    char* p = (char*)d_ws;
    auto alloc = [&](size_t bytes) {
        char* r = p;
        p += (bytes + 255) & ~(size_t)255;
        return r;
    };
    int*   pfill  = (int*)alloc((size_t)NP * 4);
    size_t zbytes = (size_t)(p - (char*)d_ws);      // zero pfill
    int*   rowptr = (int*)alloc((size_t)(N + 1) * 4);
    int*   csr    = (int*)alloc((size_t)M * 4);
    float* asv    = (float*)alloc((size_t)N * 4);
    float* adv    = (float*)alloc((size_t)N * 4);
    __hip_bfloat16* hbuf = (__hip_bfloat16*)alloc((size_t)N * CH * 2);
    // staged aliases [wedge | x2]: staged fully consumed by k_fat's build half
    // before agg1 writes x2/wedge.
    size_t wbytes = ((size_t)M * 4 + 255) & ~(size_t)255;
    size_t xbytes = (size_t)N * CH * 2;
    size_t sbytes = (size_t)NP * PCAP * 4;
    size_t blob   = wbytes + xbytes > sbytes ? wbytes + xbytes : sbytes;
    char*  bb     = alloc(blob);
    unsigned* staged = (unsigned*)bb;
    float* wedge  = (float*)bb;                      // fallback path only
    __hip_bfloat16* x2 = (__hip_bfloat16*)(bb + wbytes);

    hipMemsetAsync(d_ws, 0, zbytes, stream);

    const int gblocks = (N + 127) / 128;
    const int aggblocks = 2 * ((N + 3) / 4);   // 2 channel-halves x node cover

    k_part<<<(E + CHUNK - 1) / CHUNK, 256, 0, stream>>>(ei, pfill, staged, E, NP);
    // build (NP blocks) || gemm layer 1 (gblocks)
    k_fat<<<NP + gblocks, 256, 0, stream>>>(staged, pfill, rowptr, csr, N, E, NP,
                                            u, W1, as1, ad1, hbuf, asv, adv);

    k_fused_agg<<<aggblocks, 256, 0, stream>>>(rowptr, csr, asv, adv, wedge, hbuf, b1, x2, N);

    // layer 2 (bf16 input)
    k_gemm3<__hip_bfloat16><<<gblocks, 256, 0, stream>>>(x2, W2, as2, ad2, hbuf, asv, adv, N);
    k_fused_agg<<<aggblocks, 256, 0, stream>>>(rowptr, csr, asv, adv, wedge, hbuf, b2, x2, N);

    k_pool<<<G, 1024, 0, stream>>>(x2, batchv, (float*)d_out, N);
}

// Round 15
// 190.970 us; speedup vs baseline: 1.1098x; 1.1098x over previous
//
#include <hip/hip_runtime.h>
#include <hip/hip_bf16.h>
#include <math.h>

#define CH 128
#define PSHIFT 8              // 256 nodes per partition
#define PSIZE (1 << PSHIFT)
#define CHUNK 4096            // edges per block in k_part
#define EPT 16                // edges per thread (256 * 16 = 4096)
#define MAXP 256              // max partitions
#define PCAP 12288            // staging capacity per partition

typedef __attribute__((ext_vector_type(8))) short short8;
typedef __attribute__((ext_vector_type(4))) float f32x4;

__device__ __forceinline__ float seluf(float x) {
    const float scale = 1.0507009873554804934193349852946f;
    const float alpha = 1.6732632423543772848170429916717f;
    return x > 0.0f ? scale * x : scale * alpha * (__expf(x) - 1.0f);
}

__device__ __forceinline__ float lrelu(float x) {
    return x > 0.0f ? x : 0.2f * x;
}

__device__ __forceinline__ short bfc(float f) {
    union { __hip_bfloat16 b; short s; } u;
    u.b = __float2bfloat16(f);
    return u.s;
}

__device__ __forceinline__ unsigned pk(float lo, float hi) {
    return ((unsigned)(unsigned short)bfc(hi) << 16) | (unsigned short)bfc(lo);
}

// ---- CSR build pass A: 4B records ((dst-d0)<<24 | src), src < 2^24 ---------

__global__ __launch_bounds__(256) void k_part(const int* __restrict__ ei,
                                              int* __restrict__ pfill,
                                              unsigned* __restrict__ staged,
                                              int E, int NP) {
    __shared__ int hist[MAXP];
    __shared__ int base[MAXP];
    const int tid = threadIdx.x;
    const int j0 = blockIdx.x * CHUNK;
    for (int i = tid; i < NP; i += 256) hist[i] = 0;
    __syncthreads();
    int part[EPT], rank[EPT];
    unsigned rec[EPT];
#pragma unroll
    for (int e = 0; e < EPT; ++e) {
        int j = j0 + e * 256 + tid;
        part[e] = -1;
        if (j < E) {
            int s = ei[j], d = ei[E + j];
            part[e] = d >> PSHIFT;
            rec[e] = ((unsigned)(d & (PSIZE - 1)) << 24) | (unsigned)s;
            rank[e] = atomicAdd(&hist[part[e]], 1);
        }
    }
    __syncthreads();
    for (int i = tid; i < NP; i += 256)
        base[i] = hist[i] ? atomicAdd(&pfill[i], hist[i]) : 0;
    __syncthreads();
#pragma unroll
    for (int e = 0; e < EPT; ++e)
        if (part[e] >= 0)
            staged[(size_t)part[e] * PCAP + base[part[e]] + rank[e]] = rec[e];
}

// ---- fat kernel: CSR build pass B (blocks < NP) || GEMM layer 1 (rest) -----

__global__ __launch_bounds__(256) void k_fat(
    const unsigned* __restrict__ staged, const int* __restrict__ pfill,
    int* __restrict__ rowptr, int* __restrict__ csr, int n, int E, int NP,
    const float* __restrict__ x, const float* __restrict__ W,
    const float* __restrict__ a_s, const float* __restrict__ a_d,
    __hip_bfloat16* __restrict__ hb, float* __restrict__ as_o,
    float* __restrict__ ad_o) {
    __shared__ __align__(16) char sm[32768];
    const int tid = threadIdx.x;

    if ((int)blockIdx.x < NP) {
        // ---------------- build path ----------------
        int* lcnt = (int*)sm;            // [256]
        int* lrow = lcnt + PSIZE;        // [256]
        int* sc   = lrow + PSIZE;        // [256]
        int* psc  = sc + PSIZE;          // [256]
        const int p = blockIdx.x;
        const int d0 = p << PSHIFT;
        psc[tid] = (tid < NP) ? pfill[tid] : 0;
        lcnt[tid] = 0;
        __syncthreads();
        for (int off = 1; off < 256; off <<= 1) {
            int v = (tid >= off) ? psc[tid - off] : 0;
            __syncthreads();
            psc[tid] += v;
            __syncthreads();
        }
        const int pbase = psc[p] - pfill[p];
        const size_t rbeg = (size_t)p * PCAP;
        const size_t rend = rbeg + pfill[p];
        const int rb = pbase + d0;
        for (size_t r = rbeg + tid; r < rend; r += 256)
            atomicAdd(&lcnt[staged[r] >> 24], 1);
        __syncthreads();
        int myv = (d0 + tid < n) ? lcnt[tid] + 1 : 0;
        sc[tid] = myv;
        __syncthreads();
        for (int off = 1; off < 256; off <<= 1) {
            int v = (tid >= off) ? sc[tid - off] : 0;
            __syncthreads();
            sc[tid] += v;
            __syncthreads();
        }
        if (d0 + tid < n) {
            int rp = rb + sc[tid] - myv;
            lrow[tid] = rp;
            rowptr[d0 + tid] = rp;
            csr[rp] = d0 + tid;              // self loop
            lcnt[tid] = 0;                   // reuse as fill counter
        }
        if (p == 0 && tid == 0) rowptr[n] = E + n;
        __syncthreads();
        for (size_t r = rbeg + tid; r < rend; r += 256) {
            unsigned v = staged[r];
            int dd = v >> 24, s = (int)(v & 0xFFFFFFu);
            int pos = lrow[dd] + 1 + atomicAdd(&lcnt[dd], 1);
            csr[pos] = s;
        }
        return;
    }

    // ---------------- gemm path (layer 1, fp32 input) ----------------
    short* WB = (short*)sm;                  // 32 KB
    for (int i = tid; i < CH * CH; i += 256) {
        int k = i >> 7, c = i & 127;
        int kb = k >> 5, kk = k & 31;
        int t = c >> 4;
        int ln = (c & 15) | ((kk >> 3) << 4);
        int j = kk & 7;
        WB[(((kb << 3) + t) << 9) + (ln << 3) + j] = bfc(W[i]);
    }
    __syncthreads();
    const int bid = blockIdx.x - NP;
    const int lane = tid & 63;
    const int wid = tid >> 6;
    const int l15 = lane & 15;
    const int lhi = lane >> 4;
    float asl[8], adl[8];
#pragma unroll
    for (int t = 0; t < 8; ++t) {
        asl[t] = a_s[t * 16 + l15];
        adl[t] = a_d[t * 16 + l15];
    }
#pragma unroll
    for (int s = 0; s < 2; ++s) {
        int r0 = bid * 128 + s * 64 + wid * 16;
        if (r0 >= n) break;
        int ar = r0 + l15; if (ar >= n) ar = n - 1;
        const float* xr = x + (size_t)ar * CH + lhi * 8;
        f32x4 acc[8];
#pragma unroll
        for (int t = 0; t < 8; ++t) acc[t] = (f32x4){0.f, 0.f, 0.f, 0.f};
#pragma unroll
        for (int kb = 0; kb < 4; ++kb) {
            float4 xa = *(const float4*)(xr + kb * 32);
            float4 xb = *(const float4*)(xr + kb * 32 + 4);
            short8 af;
            af[0] = bfc(xa.x); af[1] = bfc(xa.y); af[2] = bfc(xa.z); af[3] = bfc(xa.w);
            af[4] = bfc(xb.x); af[5] = bfc(xb.y); af[6] = bfc(xb.z); af[7] = bfc(xb.w);
#pragma unroll
            for (int t = 0; t < 8; ++t) {
                short8 bv = ((const short8*)WB)[(((kb << 3) + t) << 6) | lane];
                acc[t] = __builtin_amdgcn_mfma_f32_16x16x32_bf16(af, bv, acc[t], 0, 0, 0);
            }
        }
        float pa[4] = {0.f, 0.f, 0.f, 0.f}, pd[4] = {0.f, 0.f, 0.f, 0.f};
#pragma unroll
        for (int t = 0; t < 8; ++t) {
#pragma unroll
            for (int q = 0; q < 4; ++q) {
                int row = r0 + lhi * 4 + q;
                if (row < n)
                    hb[(size_t)row * CH + t * 16 + l15] = __float2bfloat16(acc[t][q]);
                pa[q] += acc[t][q] * asl[t];
                pd[q] += acc[t][q] * adl[t];
            }
        }
#pragma unroll
        for (int q = 0; q < 4; ++q) {
#pragma unroll
            for (int o = 1; o < 16; o <<= 1) {
                pa[q] += __shfl_xor(pa[q], o);
                pd[q] += __shfl_xor(pd[q], o);
            }
        }
        if (l15 == 0) {
#pragma unroll
            for (int q = 0; q < 4; ++q) {
                int row = r0 + lhi * 4 + q;
                if (row < n) { as_o[row] = pa[q]; ad_o[row] = pd[q]; }
            }
        }
    }
}

// ---- GEMM v3 (standalone, layer 2 bf16 input) ------------------------------

template <typename T>
__global__ __launch_bounds__(256) void k_gemm3(
    const T* __restrict__ x, const float* __restrict__ W,
    const float* __restrict__ a_s, const float* __restrict__ a_d,
    __hip_bfloat16* __restrict__ hb, float* __restrict__ as_o,
    float* __restrict__ ad_o, int n) {
    __shared__ short WB[4 * 8 * 64 * 8];   // 32 KB
    const int tid = threadIdx.x;
    for (int i = tid; i < CH * CH; i += 256) {
        int k = i >> 7, c = i & 127;
        int kb = k >> 5, kk = k & 31;
        int t = c >> 4;
        int ln = (c & 15) | ((kk >> 3) << 4);
        int j = kk & 7;
        WB[(((kb << 3) + t) << 9) + (ln << 3) + j] = bfc(W[i]);
    }
    __syncthreads();
    const int lane = tid & 63;
    const int wid = tid >> 6;
    const int l15 = lane & 15;
    const int lhi = lane >> 4;
    float asl[8], adl[8];
#pragma unroll
    for (int t = 0; t < 8; ++t) {
        asl[t] = a_s[t * 16 + l15];
        adl[t] = a_d[t * 16 + l15];
    }
#pragma unroll
    for (int s = 0; s < 2; ++s) {
        int r0 = blockIdx.x * 128 + s * 64 + wid * 16;
        if (r0 >= n) break;
        int ar = r0 + l15; if (ar >= n) ar = n - 1;
        const T* xr = x + (size_t)ar * CH + lhi * 8;
        f32x4 acc[8];
#pragma unroll
        for (int t = 0; t < 8; ++t) acc[t] = (f32x4){0.f, 0.f, 0.f, 0.f};
#pragma unroll
        for (int kb = 0; kb < 4; ++kb) {
            short8 af;
            if constexpr (sizeof(T) == 4) {
                float4 xa = *(const float4*)(xr + kb * 32);
                float4 xb = *(const float4*)(xr + kb * 32 + 4);
                af[0] = bfc(xa.x); af[1] = bfc(xa.y); af[2] = bfc(xa.z); af[3] = bfc(xa.w);
                af[4] = bfc(xb.x); af[5] = bfc(xb.y); af[6] = bfc(xb.z); af[7] = bfc(xb.w);
            } else {
                af = *(const short8*)(xr + kb * 32);
            }
#pragma unroll
            for (int t = 0; t < 8; ++t) {
                short8 bv = ((const short8*)WB)[(((kb << 3) + t) << 6) | lane];
                acc[t] = __builtin_amdgcn_mfma_f32_16x16x32_bf16(af, bv, acc[t], 0, 0, 0);
            }
        }
        float pa[4] = {0.f, 0.f, 0.f, 0.f}, pd[4] = {0.f, 0.f, 0.f, 0.f};
#pragma unroll
        for (int t = 0; t < 8; ++t) {
#pragma unroll
            for (int q = 0; q < 4; ++q) {
                int row = r0 + lhi * 4 + q;
                if (row < n)
                    hb[(size_t)row * CH + t * 16 + l15] = __float2bfloat16(acc[t][q]);
                pa[q] += acc[t][q] * asl[t];
                pd[q] += acc[t][q] * adl[t];
            }
        }
#pragma unroll
        for (int q = 0; q < 4; ++q) {
#pragma unroll
            for (int o = 1; o < 16; o <<= 1) {
                pa[q] += __shfl_xor(pa[q], o);
                pd[q] += __shfl_xor(pd[q], o);
            }
        }
        if (l15 == 0) {
#pragma unroll
            for (int q = 0; q < 4; ++q) {
                int row = r0 + lhi * 4 + q;
                if (row < n) { as_o[row] = pa[q]; ad_o[row] = pd[q]; }
            }
        }
    }
}

// ---- fused softmax + aggregation: one wave per node, bf16 out --------------
// Phase C fast path: 16 edge-slots/iter, 4 uint4 gathers in flight.

__global__ __launch_bounds__(256) void k_fused_agg(
    const int* __restrict__ rowptr, const int* __restrict__ csr,
    const float* __restrict__ as_v, const float* __restrict__ ad_v,
    float* __restrict__ wedge, const __hip_bfloat16* __restrict__ hb,
    const float* __restrict__ bias, __hip_bfloat16* __restrict__ out, int n) {
    int gw = (int)((blockIdx.x * (size_t)blockDim.x + threadIdx.x) >> 6);
    int lane = threadIdx.x & 63;
    if (gw >= n) return;
    int beg = rowptr[gw], end = rowptr[gw + 1];
    int deg = end - beg;
    float adi = ad_v[gw];

    const int quarter = lane >> 4;
    const int c8 = lane & 15;
    float acc[8];
#pragma unroll
    for (int k = 0; k < 8; ++k) acc[k] = 0.f;
    float inv;

    if (deg <= 64) {
        bool valid = lane < deg;
        int src = valid ? csr[beg + lane] : 0;
        float e = valid ? lrelu(as_v[src] + adi) : -1e30f;
        float m = e;
#pragma unroll
        for (int o = 32; o > 0; o >>= 1) m = fmaxf(m, __shfl_xor(m, o));
        float w = valid ? __expf(e - m) : 0.f;
        float s = w;
#pragma unroll
        for (int o = 32; o > 0; o >>= 1) s += __shfl_xor(s, o);
        inv = 1.0f / s;
        // 16 slots/iter; slots >= deg carry w=0, src=0; indices always < 64.
        for (int b = 0; b < deg; b += 16) {
            int i0 = b + quarter, i1 = b + 4 + quarter;
            int i2 = b + 8 + quarter, i3 = b + 12 + quarter;
            float w0 = __shfl(w, i0), w1 = __shfl(w, i1);
            float w2 = __shfl(w, i2), w3 = __shfl(w, i3);
            int s0 = __shfl(src, i0), s1 = __shfl(src, i1);
            int s2 = __shfl(src, i2), s3 = __shfl(src, i3);
            uint4 hv0 = ((const uint4*)hb)[(size_t)s0 * 16 + c8];
            uint4 hv1 = ((const uint4*)hb)[(size_t)s1 * 16 + c8];
            uint4 hv2 = ((const uint4*)hb)[(size_t)s2 * 16 + c8];
            uint4 hv3 = ((const uint4*)hb)[(size_t)s3 * 16 + c8];
            acc[0] += w0 * __uint_as_float(hv0.x << 16);
            acc[1] += w0 * __uint_as_float(hv0.x & 0xffff0000u);
            acc[2] += w0 * __uint_as_float(hv0.y << 16);
            acc[3] += w0 * __uint_as_float(hv0.y & 0xffff0000u);
            acc[4] += w0 * __uint_as_float(hv0.z << 16);
            acc[5] += w0 * __uint_as_float(hv0.z & 0xffff0000u);
            acc[6] += w0 * __uint_as_float(hv0.w << 16);
            acc[7] += w0 * __uint_as_float(hv0.w & 0xffff0000u);
            acc[0] += w1 * __uint_as_float(hv1.x << 16);
            acc[1] += w1 * __uint_as_float(hv1.x & 0xffff0000u);
            acc[2] += w1 * __uint_as_float(hv1.y << 16);
            acc[3] += w1 * __uint_as_float(hv1.y & 0xffff0000u);
            acc[4] += w1 * __uint_as_float(hv1.z << 16);
            acc[5] += w1 * __uint_as_float(hv1.z & 0xffff0000u);
            acc[6] += w1 * __uint_as_float(hv1.w << 16);
            acc[7] += w1 * __uint_as_float(hv1.w & 0xffff0000u);
            acc[0] += w2 * __uint_as_float(hv2.x << 16);
            acc[1] += w2 * __uint_as_float(hv2.x & 0xffff0000u);
            acc[2] += w2 * __uint_as_float(hv2.y << 16);
            acc[3] += w2 * __uint_as_float(hv2.y & 0xffff0000u);
            acc[4] += w2 * __uint_as_float(hv2.z << 16);
            acc[5] += w2 * __uint_as_float(hv2.z & 0xffff0000u);
            acc[6] += w2 * __uint_as_float(hv2.w << 16);
            acc[7] += w2 * __uint_as_float(hv2.w & 0xffff0000u);
            acc[0] += w3 * __uint_as_float(hv3.x << 16);
            acc[1] += w3 * __uint_as_float(hv3.x & 0xffff0000u);
            acc[2] += w3 * __uint_as_float(hv3.y << 16);
            acc[3] += w3 * __uint_as_float(hv3.y & 0xffff0000u);
            acc[4] += w3 * __uint_as_float(hv3.z << 16);
            acc[5] += w3 * __uint_as_float(hv3.z & 0xffff0000u);
            acc[6] += w3 * __uint_as_float(hv3.w << 16);
            acc[7] += w3 * __uint_as_float(hv3.w & 0xffff0000u);
        }
    } else {
        float m = -1e30f;
        for (int p = beg + lane; p < end; p += 64) {
            float e = lrelu(as_v[csr[p]] + adi);
            wedge[p] = e;
            m = fmaxf(m, e);
        }
#pragma unroll
        for (int o = 32; o > 0; o >>= 1) m = fmaxf(m, __shfl_xor(m, o));
        float s = 0.f;
        for (int p = beg + lane; p < end; p += 64) {
            float wv = __expf(wedge[p] - m);
            wedge[p] = wv;
            s += wv;
        }
#pragma unroll
        for (int o = 32; o > 0; o >>= 1) s += __shfl_xor(s, o);
        inv = 1.0f / s;
        for (int p = beg; p < end; p += 8) {
            int p0 = p + quarter, p1 = p + 4 + quarter;
            float w0 = 0.f, w1 = 0.f;
            int s0 = 0, s1 = 0;
            if (p0 < end) { w0 = wedge[p0]; s0 = csr[p0]; }
            if (p1 < end) { w1 = wedge[p1]; s1 = csr[p1]; }
            uint4 hv0 = ((const uint4*)hb)[(size_t)s0 * 16 + c8];
            uint4 hv1 = ((const uint4*)hb)[(size_t)s1 * 16 + c8];
            acc[0] += w0 * __uint_as_float(hv0.x << 16);
            acc[1] += w0 * __uint_as_float(hv0.x & 0xffff0000u);
            acc[2] += w0 * __uint_as_float(hv0.y << 16);
            acc[3] += w0 * __uint_as_float(hv0.y & 0xffff0000u);
            acc[4] += w0 * __uint_as_float(hv0.z << 16);
            acc[5] += w0 * __uint_as_float(hv0.z & 0xffff0000u);
            acc[6] += w0 * __uint_as_float(hv0.w << 16);
            acc[7] += w0 * __uint_as_float(hv0.w & 0xffff0000u);
            acc[0] += w1 * __uint_as_float(hv1.x << 16);
            acc[1] += w1 * __uint_as_float(hv1.x & 0xffff0000u);
            acc[2] += w1 * __uint_as_float(hv1.y << 16);
            acc[3] += w1 * __uint_as_float(hv1.y & 0xffff0000u);
            acc[4] += w1 * __uint_as_float(hv1.z << 16);
            acc[5] += w1 * __uint_as_float(hv1.z & 0xffff0000u);
            acc[6] += w1 * __uint_as_float(hv1.w << 16);
            acc[7] += w1 * __uint_as_float(hv1.w & 0xffff0000u);
        }
    }
#pragma unroll
    for (int k = 0; k < 8; ++k) {
        acc[k] += __shfl_xor(acc[k], 16);
        acc[k] += __shfl_xor(acc[k], 32);
    }
    if (quarter == 0) {
        const float4 bv0 = ((const float4*)bias)[c8 * 2];
        const float4 bv1 = ((const float4*)bias)[c8 * 2 + 1];
        float o0 = seluf(acc[0] * inv + bv0.x);
        float o1 = seluf(acc[1] * inv + bv0.y);
        float o2 = seluf(acc[2] * inv + bv0.z);
        float o3 = seluf(acc[3] * inv + bv0.w);
        float o4 = seluf(acc[4] * inv + bv1.x);
        float o5 = seluf(acc[5] * inv + bv1.y);
        float o6 = seluf(acc[6] * inv + bv1.z);
        float o7 = seluf(acc[7] * inv + bv1.w);
        uint4 ov;
        ov.x = pk(o0, o1);
        ov.y = pk(o2, o3);
        ov.z = pk(o4, o5);
        ov.w = pk(o6, o7);
        ((uint4*)out)[(size_t)gw * 16 + c8] = ov;
    }
}

// ---- global mean pool: single launch, 16 waves per graph -------------------

__device__ int lower_bound_dev(const int* a, int n, int key) {
    int lo = 0, hi = n;
    while (lo < hi) {
        int mid = (lo + hi) >> 1;
        if (a[mid] < key) lo = mid + 1; else hi = mid;
    }
    return lo;
}

__global__ __launch_bounds__(1024) void k_pool(const __hip_bfloat16* __restrict__ x,
                                               const int* __restrict__ batchv,
                                               float* __restrict__ outp, int n) {
    int g = blockIdx.x;
    int lo = lower_bound_dev(batchv, n, g);
    int hi = lower_bound_dev(batchv, n, g + 1);
    int lane = threadIdx.x & 63, wv = threadIdx.x >> 6;   // wv: 0..15
    float sx0 = 0.f, sy0 = 0.f, sx1 = 0.f, sy1 = 0.f;
    int i = lo + wv;
    for (; i + 16 < hi; i += 32) {
        unsigned u0 = ((const unsigned*)x)[(size_t)i * 64 + lane];
        unsigned u1 = ((const unsigned*)x)[(size_t)(i + 16) * 64 + lane];
        sx0 += __uint_as_float(u0 << 16);
        sy0 += __uint_as_float(u0 & 0xffff0000u);
        sx1 += __uint_as_float(u1 << 16);
        sy1 += __uint_as_float(u1 & 0xffff0000u);
    }
    if (i < hi) {
        unsigned u0 = ((const unsigned*)x)[(size_t)i * 64 + lane];
        sx0 += __uint_as_float(u0 << 16);
        sy0 += __uint_as_float(u0 & 0xffff0000u);
    }
    __shared__ float2 red[16][64];
    red[wv][lane] = make_float2(sx0 + sx1, sy0 + sy1);
    __syncthreads();
    if (wv == 0) {
        float ax = 0.f, ay = 0.f;
#pragma unroll
        for (int s = 0; s < 16; ++s) { ax += red[s][lane].x; ay += red[s][lane].y; }
        int cnt = hi - lo; if (cnt < 1) cnt = 1;
        float invc = 1.0f / (float)cnt;
        outp[(size_t)g * CH + 2 * lane] = ax * invc;
        outp[(size_t)g * CH + 2 * lane + 1] = ay * invc;
    }
}

// ---- orchestration ---------------------------------------------------------

extern "C" void kernel_launch(void* const* d_in, const int* in_sizes, int n_in,
                              void* d_out, int out_size, void* d_ws, size_t ws_size,
                              hipStream_t stream) {
    const float* u   = (const float*)d_in[0];
    const float* W1  = (const float*)d_in[1];
    const float* as1 = (const float*)d_in[2];
    const float* ad1 = (const float*)d_in[3];
    const float* b1  = (const float*)d_in[4];
    const float* W2  = (const float*)d_in[5];
    const float* as2 = (const float*)d_in[6];
    const float* ad2 = (const float*)d_in[7];
    const float* b2  = (const float*)d_in[8];
    const int* ei    = (const int*)d_in[9];
    const int* batchv= (const int*)d_in[10];

    const int N = in_sizes[0] / CH;
    const int E = in_sizes[9] / 2;
    const int M = E + N;
    const int NP = (N + PSIZE - 1) >> PSHIFT;
    const int G = out_size / CH;

    char* p = (char*)d_ws;
    auto alloc = [&](size_t bytes) {
        char* r = p;
        p += (bytes + 255) & ~(size_t)255;
        return r;
    };
    int*   pfill  = (int*)alloc((size_t)NP * 4);
    size_t zbytes = (size_t)(p - (char*)d_ws);      // zero pfill
    int*   rowptr = (int*)alloc((size_t)(N + 1) * 4);
    int*   csr    = (int*)alloc((size_t)M * 4);
    float* asv    = (float*)alloc((size_t)N * 4);
    float* adv    = (float*)alloc((size_t)N * 4);
    __hip_bfloat16* hbuf = (__hip_bfloat16*)alloc((size_t)N * CH * 2);
    // staged aliases [wedge | x2]: staged fully consumed by k_fat's build half
    // before agg1 writes x2/wedge.
    size_t wbytes = ((size_t)M * 4 + 255) & ~(size_t)255;
    size_t xbytes = (size_t)N * CH * 2;
    size_t sbytes = (size_t)NP * PCAP * 4;
    size_t blob   = wbytes + xbytes > sbytes ? wbytes + xbytes : sbytes;
    char*  bb     = alloc(blob);
    unsigned* staged = (unsigned*)bb;
    float* wedge  = (float*)bb;                      // fallback path only
    __hip_bfloat16* x2 = (__hip_bfloat16*)(bb + wbytes);

    hipMemsetAsync(d_ws, 0, zbytes, stream);

    const int gblocks = (N + 127) / 128;

    k_part<<<(E + CHUNK - 1) / CHUNK, 256, 0, stream>>>(ei, pfill, staged, E, NP);
    // build (NP blocks) || gemm layer 1 (gblocks)
    k_fat<<<NP + gblocks, 256, 0, stream>>>(staged, pfill, rowptr, csr, N, E, NP,
                                            u, W1, as1, ad1, hbuf, asv, adv);

    k_fused_agg<<<(N * 64 + 255) / 256, 256, 0, stream>>>(rowptr, csr, asv, adv, wedge, hbuf, b1, x2, N);

    // layer 2 (bf16 input)
    k_gemm3<__hip_bfloat16><<<gblocks, 256, 0, stream>>>(x2, W2, as2, ad2, hbuf, asv, adv, N);
    k_fused_agg<<<(N * 64 + 255) / 256, 256, 0, stream>>>(rowptr, csr, asv, adv, wedge, hbuf, b2, x2, N);

    k_pool<<<G, 1024, 0, stream>>>(x2, batchv, (float*)d_out, N);
}